// Round 9
// baseline (382.674 us; speedup 1.0000x reference)
//
#include <hip/hip_runtime.h>
#include <math.h>

#define BB 16
#define NN 512
#define HID 32

#define HALO 16
#define TW 96        // logical tile width (64 + 2*HALO)
#define TWP 97       // LDS pitch: 97 % 32 == 1 -> conflict-free Phase D
#define OT 64

// fast tanh-approx GELU: gelu(v) = v / (1 + exp2(K1*v + K2*v^3))
#define GELU_K1 (-2.302208201f)
#define GELU_K2 (-0.102944244f)

// LFA angle step 2*pi/513: rotation recurrence cos/sin
#define CDR 0.99992499f
#define SDR 0.012247618f
// 1/513 (angles in revolutions for v_sin_f32/v_cos_f32: D = sin(S0*2pi))
#define REVS 0.0019493177f

// ---------------------------------------------------------------------------
// LFA map (R10-proven + HW sin/cos, ~5 us). MEASURED (rounds 2 & 3): folding
// this into fused_cycle in ANY form tips it over the VGPR cliff. FROZEN.
// ---------------------------------------------------------------------------
__global__ __launch_bounds__(256) void lfa_kernel(const float* __restrict__ kernelA,
                                                  float* __restrict__ lfa) {
    const int t = threadIdx.x;
    const int strip = t & 127;           // 128 strips of 4 cols
    const int i = blockIdx.y * 2 + (t >> 7);
    const int b = blockIdx.z;
    const int j0 = strip * 4;
    const float* a = kernelA + b * 9;
    float a0 = a[0], a1 = a[1], a2 = a[2], a3 = a[3], a4 = a[4];
    float a5 = a[5], a6 = a[6], a7 = a[7], a8 = a[8];
    const float A35 = a3 + a5, A17 = a1 + a7, A08 = a0 + a8, A26 = a2 + a6;
    const float B53 = a5 - a3, B71 = a7 - a1, B80 = a8 - a0, B26 = a2 - a6;
    const float tau = 0.5f / a4;

    float r1 = (float)(j0 - NN / 2) * REVS;   // revolutions, |r| < 0.5
    float r2 = (float)(i - NN / 2) * REVS;
    float s1 = __builtin_amdgcn_sinf(r1);
    float c1 = __builtin_amdgcn_cosf(r1);
    float s2 = __builtin_amdgcn_sinf(r2);
    float c2 = __builtin_amdgcn_cosf(r2);

    float out[4];
#pragma unroll
    for (int k = 0; k < 4; ++k) {
        float cc = c1 * c2, ss = s1 * s2, sc = s1 * c2, cs = c1 * s2;
        float cpp = cc - ss, cpm = cc + ss, spp = sc + cs, spm = sc - cs;
        float re = fmaf(A35, c1, a4); re = fmaf(A17, c2, re);
        re = fmaf(A08, cpp, re);      re = fmaf(A26, cpm, re);
        float im = B53 * s1;          im = fmaf(B71, s2, im);
        im = fmaf(B80, spp, im);      im = fmaf(B26, spm, im);
        float zre = fmaf(-tau, re, 1.0f);
        float zim = tau * im;
        float m2 = fmaf(zre, zre, zim * zim);
        out[k] = m2 * m2 * sqrtf(m2);   // |z|^5
        float tt = s1 * SDR;
        float ns = fmaf(s1, CDR, c1 * SDR);
        c1 = fmaf(c1, CDR, -tt);
        s1 = ns;
    }
    float4 ov = {out[0], out[1], out[2], out[3]};
    *(float4*)(lfa + (size_t)b * NN * NN + (size_t)i * NN + j0) = ov;
}

// ---------------------------------------------------------------------------
// One full cycle. ROUND 9: occupancy restructure — 512 threads (32x16),
// 6 rows/thread. Rationale (round-8 counters): per-thread state
// (cur[12][3]+frt[12][3] = 72 VGPR) pinned the kernel at 116 VGPR -> 4
// waves/SIMD; halving rows/thread targets <=85 VGPR -> 6 waves/SIMD,
// 3 blocks/CU x 8 waves = 24 waves/CU (+50% latency hiding). Identical
// per-cell arithmetic & fma order -> bit-exact vs rounds 5/8.
// Skeleton: round-5 PROVEN 2-barrier sweep (publish border rows into the sx
// tile) + round-8 PROVEN shuffle L/R halo (bit-exact; wave-boundary garbage
// only feeds vC-masked cells). Taps in CANONICAL 9-TAP FORM — rounds 6/7
// failed (absmax 3.9e-2) from one dropped tap during an fma-chain rewrite;
// never compress these chains.
// Ledger: DO NOT use multi-arg __launch_bounds__ (round 1: 64-VGPR bucket +
// spills). DO NOT inline LFA (rounds 2/3: VGPR cliff).
// FIRST: x0 = 0, sweep 0 collapses to cur = mask*(tau*f); tile fill skipped;
//        zeroes the accumulator/counter slots (replaces hipMemsetAsync).
// RES:   cycle-3 variant (rounds 2/4/5/8 verified). No x store. r_final =
//        r_pre - A(H) via H-ring exchange through the LDS tile (ring cells
//        are bit-exact recomputations: contamination depth 10 < 15).
//        Block-reduces sum(r^2), sum(f^2); LAST block (device counter)
//        computes the final norm -> no finalize dispatch.
// ---------------------------------------------------------------------------
template <bool FIRST, bool RES>
__global__ __launch_bounds__(512) void fused_cycle(
        const float* __restrict__ xin, float* __restrict__ xout,
        const float* __restrict__ f, const float* __restrict__ kernelA,
        const float* __restrict__ lfa,
        const float* __restrict__ W1, const float* __restrict__ b1,
        const float* __restrict__ W2, const float* __restrict__ b2,
        float* __restrict__ accp, float* __restrict__ outp) {
    __shared__ float sxraw[98 * TWP + 2];
    float* sx = sxraw + TWP + 1;   // logical origin (0,0); row r col c -> sx[r*TWP+c]
    const int tx = threadIdx.x;   // 0..31
    const int ty = threadIdx.y;   // 0..15
    const int t  = ty * 32 + tx;  // 0..511
    const int b  = blockIdx.z;
    const int gy0 = blockIdx.y * OT;
    const int gx0 = blockIdx.x * OT;
    const int goi = gy0 - HALO;
    const int goj = gx0 - HALO;
    const float* fg = f + (size_t)b * NN * NN;
    const float* ag = kernelA + b * 9;   // uniform -> s_load
    const float ar0 = ag[0], ar1 = ag[1], ar2 = ag[2], ar3 = ag[3], ar4 = ag[4];
    const float ar5 = ag[5], ar6 = ag[6], ar7 = ag[7], ar8 = ag[8];
    const float tau = 0.5f / ar4;
    const float s0 = tau * ar0, q1 = tau * ar1, q2 = tau * ar2, q3 = tau * ar3;
    const float q4 = tau * ar4, q5 = tau * ar5, q6 = tau * ar6, q7 = tau * ar7;
    const float q8 = tau * ar8;

    if (FIRST) {
        if (t == 0 && (blockIdx.x | blockIdx.y | blockIdx.z) == 0) {
            accp[0] = 0.f;
            accp[1] = 0.f;
            ((unsigned int*)accp)[2] = 0u;
        }
    }

    // ---- zero the guard ring (top band, shared L/R col guards, bottom band)
    if (t < 98) sxraw[t] = 0.f;                 // logical row -1, col -1..96
    if (t < 96) sxraw[97 + 97 * t] = 0.f;       // col -1 of row t (== col 96 of row t-1)
    if (t < 98) sxraw[9409 + t] = 0.f;          // logical row 96, col -1..96

    // ---- Phase A: tile -> LDS (interior 96x96), float4 strips ----
    if (!FIRST) {
        const float* xg = xin + (size_t)b * NN * NN;
#pragma unroll
        for (int k = 0; k < 5; ++k) {
            int idx = t + k * 512;               // 2304 strips total
            if (idx < 2304) {
                int row = idx / 24;
                int c4  = (idx - row * 24) * 4;
                int gi = goi + row, gj = goj + c4;
                float4 v = {0.f, 0.f, 0.f, 0.f};
                if ((unsigned)gi < NN && (unsigned)gj < NN)
                    v = *(const float4*)(xg + (size_t)gi * NN + gj);
                float* d = sx + row * TWP + c4;
                d[0] = v.x; d[1] = v.y; d[2] = v.z; d[3] = v.w;
            }
        }
    }

    const int R0 = ty * 6, C0 = tx * 3;
    const float* pb  = sx + (R0 - 1) * TWP + (C0 - 1);
    float*       pwv = sx + R0 * TWP + C0;

    float vR[6], vC[3];
#pragma unroll
    for (int r = 0; r < 6; ++r) {
        int R = R0 + r, gi = goi + R;
        vR[r] = (R >= 1 && R < TW - 1 && gi >= 0 && gi < NN) ? 1.f : 0.f;
    }
#pragma unroll
    for (int c = 0; c < 3; ++c) {
        int C = C0 + c, gj = goj + C;
        vC[c] = (C >= 1 && C < TW - 1 && gj >= 0 && gj < NN) ? 1.f : 0.f;
    }

    float frt[6][3];
#pragma unroll
    for (int r = 0; r < 6; ++r) {
        int gi = goi + R0 + r;
#pragma unroll
        for (int c = 0; c < 3; ++c) {
            int gj = goj + C0 + c;
            frt[r][c] = (gi >= 0 && gi < NN && gj >= 0 && gj < NN)
                            ? tau * fg[gi * NN + gj] : 0.f;
        }
    }

    __syncthreads();   // tile + guards visible

    // ---- Phase B: own cells -> registers ----
    float cur[6][3];
    if (FIRST) {
        // collapsed sweep 0: x1 = mask * (tau*f); publish rows 0/5
#pragma unroll
        for (int r = 0; r < 6; ++r)
#pragma unroll
            for (int c = 0; c < 3; ++c)
                cur[r][c] = (vR[r] * vC[c]) * frt[r][c];
        pwv[0] = cur[0][0]; pwv[1] = cur[0][1]; pwv[2] = cur[0][2];
        pwv[5 * TWP] = cur[5][0]; pwv[5 * TWP + 1] = cur[5][1];
        pwv[5 * TWP + 2] = cur[5][2];
        __syncthreads();   // sweep-0 borders visible
    } else {
#pragma unroll
        for (int r = 0; r < 6; ++r) {
            cur[r][0] = pwv[r * TWP];
            cur[r][1] = pwv[r * TWP + 1];
            cur[r][2] = pwv[r * TWP + 2];
        }
    }

    // ---- Phase C: sweeps (FIRST starts at s=1: sweep 0 was collapsed) ----
    for (int s = FIRST ? 1 : 0; s < 10; ++s) {
        // top/bot halo from sx rows R0-1 / R0+6 (neighbors' published 5/0)
        float top0 = pb[0], top1 = pb[1], top2 = pb[2], top3 = pb[3], top4 = pb[4];
        float bot0 = pb[7 * TWP],     bot1 = pb[7 * TWP + 1],
              bot2 = pb[7 * TWP + 2], bot3 = pb[7 * TWP + 3],
              bot4 = pb[7 * TWP + 4];
        float pm0 = top1, pm1v = top2, pm2 = top3;
        float Lm1 = top0, Rm1 = top4;
        // L/R halo via wave shuffles (bit-exact: neighbor lane registers =
        // previous-sweep values; boundary garbage vC-masked)
        float Lc = __shfl_up(cur[0][2], 1);
        float Rc = __shfl_down(cur[0][0], 1);
#pragma unroll
        for (int r = 0; r < 6; ++r) {
            float n0, n1, n2, Lp, Rp;
            if (r < 5) {
                n0 = cur[r + 1][0]; n1 = cur[r + 1][1]; n2 = cur[r + 1][2];
                Lp = __shfl_up(cur[r + 1][2], 1);
                Rp = __shfl_down(cur[r + 1][0], 1);
            } else {
                n0 = bot1; n1 = bot2; n2 = bot3; Lp = bot0; Rp = bot4;
            }
            float o0 = cur[r][0], o1 = cur[r][1], o2 = cur[r][2];
            // c = 0  (canonical 9-tap)
            {
                float ax = s0 * Lm1;
                ax = fmaf(q1, pm0, ax); ax = fmaf(q2, pm1v, ax);
                ax = fmaf(q3, Lc, ax);  ax = fmaf(q4, o0, ax);
                ax = fmaf(q5, o1, ax);  ax = fmaf(q6, Lp, ax);
                ax = fmaf(q7, n0, ax);  ax = fmaf(q8, n1, ax);
                cur[r][0] = fmaf(vR[r] * vC[0], frt[r][0] - ax, o0);
            }
            // c = 1
            {
                float ax = s0 * pm0;
                ax = fmaf(q1, pm1v, ax); ax = fmaf(q2, pm2, ax);
                ax = fmaf(q3, o0, ax);   ax = fmaf(q4, o1, ax);
                ax = fmaf(q5, o2, ax);   ax = fmaf(q6, n0, ax);
                ax = fmaf(q7, n1, ax);   ax = fmaf(q8, n2, ax);
                cur[r][1] = fmaf(vR[r] * vC[1], frt[r][1] - ax, o1);
            }
            // c = 2
            {
                float ax = s0 * pm1v;
                ax = fmaf(q1, pm2, ax); ax = fmaf(q2, Rm1, ax);
                ax = fmaf(q3, o1, ax);  ax = fmaf(q4, o2, ax);
                ax = fmaf(q5, Rc, ax);  ax = fmaf(q6, n1, ax);
                ax = fmaf(q7, n2, ax);  ax = fmaf(q8, Rp, ax);
                cur[r][2] = fmaf(vR[r] * vC[2], frt[r][2] - ax, o2);
            }
            pm0 = o0; pm1v = o1; pm2 = o2;
            Lm1 = Lc; Rm1 = Rc; Lc = Lp; Rc = Rp;
        }
        __syncthreads();   // all halo reads done
        if (s < 9) {
            // publish rows 0/5 only (6 stores)
            pwv[0] = cur[0][0]; pwv[1] = cur[0][1]; pwv[2] = cur[0][2];
            pwv[5 * TWP] = cur[5][0]; pwv[5 * TWP + 1] = cur[5][1];
            pwv[5 * TWP + 2] = cur[5][2];
        } else {
            // final sweep: publish ALL cells for the correction phase
#pragma unroll
            for (int r = 0; r < 6; ++r) {
                pwv[r * TWP] = cur[r][0];
                pwv[r * TWP + 1] = cur[r][1];
                pwv[r * TWP + 2] = cur[r][2];
            }
        }
        __syncthreads();   // writes visible
    }

    // ---- Phase D: remapped correction, exactly 1x MLP work ----
    // thread t -> output row orow = t/8 (0..63), 8-col segment oseg = t%8
    // Pitch 97: bank = (orow + 8*oseg + k + const) mod 32 -> 2 lanes/bank (free).
    const int orow = t >> 3;
    const int oseg = t & 7;
    const int Rl = HALO + orow;           // 16..79
    const int Cl0 = HALO + oseg * 8;      // 16,24,...,72
    const float* pw = sx + (Rl - 1) * TWP + (Cl0 - 1);
    const int gi = gy0 + orow;
    const int gjb = gx0 + oseg * 8;
    const float b2v = b2[0];

    if (!RES) {
        float w0[10], w1[10], w2[10];
#pragma unroll
        for (int k = 0; k < 10; ++k) {
            w0[k] = pw[k];
            w1[k] = pw[TWP + k];
            w2[k] = pw[2 * TWP + k];
        }
        const float4* f4 = (const float4*)(fg + (size_t)gi * NN + gjb);
        const float4* l4 = (const float4*)(lfa + (size_t)b * NN * NN + (size_t)gi * NN + gjb);
        float fv[8], lv[8];
#pragma unroll
        for (int q = 0; q < 2; ++q) {
            float4 fq = f4[q], lq = l4[q];
            fv[q * 4] = fq.x; fv[q * 4 + 1] = fq.y; fv[q * 4 + 2] = fq.z; fv[q * 4 + 3] = fq.w;
            lv[q * 4] = lq.x; lv[q * 4 + 1] = lq.y; lv[q * 4 + 2] = lq.z; lv[q * 4 + 3] = lq.w;
        }
        float rv[8];
#pragma unroll
        for (int k = 0; k < 8; ++k) {
            float ax = ar0 * w0[k];
            ax = fmaf(ar1, w0[k + 1], ax); ax = fmaf(ar2, w0[k + 2], ax);
            ax = fmaf(ar3, w1[k], ax);     ax = fmaf(ar4, w1[k + 1], ax);
            ax = fmaf(ar5, w1[k + 2], ax); ax = fmaf(ar6, w2[k], ax);
            ax = fmaf(ar7, w2[k + 1], ax); ax = fmaf(ar8, w2[k + 2], ax);
            rv[k] = fv[k] - ax;
        }
        float acc[8];
#pragma unroll
        for (int k = 0; k < 8; ++k) acc[k] = 0.f;
        for (int hh = 0; hh < HID; ++hh) {
            float w1a = W1[2 * hh], w1b = W1[2 * hh + 1], bb = b1[hh], wo = W2[hh];
#pragma unroll
            for (int k = 0; k < 8; ++k) {
                float v = fmaf(w1a, lv[k], fmaf(w1b, rv[k], bb));
                float m = v * fmaf(GELU_K2, v * v, GELU_K1);
                float e2 = __builtin_amdgcn_exp2f(m);
                float g = v * __builtin_amdgcn_rcpf(1.0f + e2);
                acc[k] = fmaf(wo, g, acc[k]);
            }
        }
        float4* xo4 = (float4*)(xout + (size_t)b * NN * NN + (size_t)gi * NN + gjb);
#pragma unroll
        for (int q = 0; q < 2; ++q) {
            float4 ov;
            ov.x = w1[q * 4 + 1] + acc[q * 4] + b2v;
            ov.y = w1[q * 4 + 2] + acc[q * 4 + 1] + b2v;
            ov.z = w1[q * 4 + 3] + acc[q * 4 + 2] + b2v;
            ov.w = w1[q * 4 + 4] + acc[q * 4 + 3] + b2v;
            xo4[q] = ov;
        }
    } else {
        // ---- register-light residual path (rounds 2/4/5/8 verified) ----
        // r_pre = f - A(w), row-by-row so only 10 w values are live at once
        float rv[8];
        {
            float w[10];
#pragma unroll
            for (int k = 0; k < 10; ++k) w[k] = pw[k];
#pragma unroll
            for (int k = 0; k < 8; ++k) {
                float ax = ar0 * w[k];
                ax = fmaf(ar1, w[k + 1], ax);
                rv[k] = fmaf(ar2, w[k + 2], ax);
            }
#pragma unroll
            for (int k = 0; k < 10; ++k) w[k] = pw[TWP + k];
#pragma unroll
            for (int k = 0; k < 8; ++k) {
                float ax = fmaf(ar3, w[k], rv[k]);
                ax = fmaf(ar4, w[k + 1], ax);
                rv[k] = fmaf(ar5, w[k + 2], ax);
            }
#pragma unroll
            for (int k = 0; k < 10; ++k) w[k] = pw[2 * TWP + k];
#pragma unroll
            for (int k = 0; k < 8; ++k) {
                float ax = fmaf(ar6, w[k], rv[k]);
                ax = fmaf(ar7, w[k + 1], ax);
                rv[k] = fmaf(ar8, w[k + 2], ax);
            }
        }
        float f2 = 0.f;
        {
            const float4* f4 = (const float4*)(fg + (size_t)gi * NN + gjb);
#pragma unroll
            for (int q = 0; q < 2; ++q) {
                float4 fq = f4[q];
                rv[q * 4]     = fq.x - rv[q * 4];
                rv[q * 4 + 1] = fq.y - rv[q * 4 + 1];
                rv[q * 4 + 2] = fq.z - rv[q * 4 + 2];
                rv[q * 4 + 3] = fq.w - rv[q * 4 + 3];
                f2 = fmaf(fq.x, fq.x, f2);
                f2 = fmaf(fq.y, fq.y, f2);
                f2 = fmaf(fq.z, fq.z, f2);
                f2 = fmaf(fq.w, fq.w, f2);
            }
        }

        // ---- ring-cell H: the 66x66 frame around the 64x64 output region.
        // 260 cells over 512 threads: t < 260 takes exactly one.
        float Hr0 = 0.f;
        int hoff0 = 0;
        if (t < 260) {
            int R, C;
            if (t < 66)        { R = 15; C = 15 + t; }
            else if (t < 132)  { R = 80; C = t - 51; }
            else if (t < 196)  { R = t - 116; C = 15; }
            else               { R = t - 180; C = 80; }
            hoff0 = R * TWP + C;
            int rgi = goi + R, rgj = goj + C;
            if (rgi >= 0 && rgi < NN && rgj >= 0 && rgj < NN) {
                const float* pr = sx + (R - 1) * TWP + (C - 1);
                float u0 = pr[0], u1 = pr[1], u2 = pr[2];
                float m0 = pr[TWP], m1 = pr[TWP + 1], m2 = pr[TWP + 2];
                float d0 = pr[2 * TWP], d1 = pr[2 * TWP + 1], d2 = pr[2 * TWP + 2];
                float ax = ar0 * u0;
                ax = fmaf(ar1, u1, ax); ax = fmaf(ar2, u2, ax);
                ax = fmaf(ar3, m0, ax); ax = fmaf(ar4, m1, ax);
                ax = fmaf(ar5, m2, ax); ax = fmaf(ar6, d0, ax);
                ax = fmaf(ar7, d1, ax); ax = fmaf(ar8, d2, ax);
                float rp = fg[(size_t)rgi * NN + rgj] - ax;
                float lf = lfa[(size_t)b * NN * NN + (size_t)rgi * NN + rgj];
                float av = 0.f;
                for (int hh = 0; hh < HID; ++hh) {
                    float w1a = W1[2 * hh], w1b = W1[2 * hh + 1], bbv = b1[hh], wo = W2[hh];
                    float v = fmaf(w1a, lf, fmaf(w1b, rp, bbv));
                    float m = v * fmaf(GELU_K2, v * v, GELU_K1);
                    float e2 = __builtin_amdgcn_exp2f(m);
                    float gg = v * __builtin_amdgcn_rcpf(1.0f + e2);
                    av = fmaf(wo, gg, av);
                }
                Hr0 = av + b2v;
            }
        }

        // ---- own-cell MLP: lv loaded just-in-time ----
        float acc[8];
#pragma unroll
        for (int k = 0; k < 8; ++k) acc[k] = 0.f;
        {
            float lv[8];
            const float4* l4 = (const float4*)(lfa + (size_t)b * NN * NN + (size_t)gi * NN + gjb);
#pragma unroll
            for (int q = 0; q < 2; ++q) {
                float4 lq = l4[q];
                lv[q * 4] = lq.x; lv[q * 4 + 1] = lq.y;
                lv[q * 4 + 2] = lq.z; lv[q * 4 + 3] = lq.w;
            }
            for (int hh = 0; hh < HID; ++hh) {
                float w1a = W1[2 * hh], w1b = W1[2 * hh + 1], bb = b1[hh], wo = W2[hh];
#pragma unroll
                for (int k = 0; k < 8; ++k) {
                    float v = fmaf(w1a, lv[k], fmaf(w1b, rv[k], bb));
                    float m = v * fmaf(GELU_K2, v * v, GELU_K1);
                    float e2 = __builtin_amdgcn_exp2f(m);
                    float g = v * __builtin_amdgcn_rcpf(1.0f + e2);
                    acc[k] = fmaf(wo, g, acc[k]);
                }
            }
        }

        __syncthreads();   // all LDS w-reads (own + ring) complete
        // publish H on [15,81)^2 in place over the sweep tile
        float* ph = sx + Rl * TWP + Cl0;
#pragma unroll
        for (int k = 0; k < 8; ++k) ph[k] = acc[k] + b2v;
        if (t < 260) sx[hoff0] = Hr0;
        __syncthreads();   // H tile visible

        // r_final = r_pre - A(H), row-by-row
        float rr = 0.f;
        {
            float hr[10];
#pragma unroll
            for (int k = 0; k < 10; ++k) hr[k] = pw[k];
#pragma unroll
            for (int k = 0; k < 8; ++k) {
                float ax = ar0 * hr[k];
                ax = fmaf(ar1, hr[k + 1], ax);
                ax = fmaf(ar2, hr[k + 2], ax);
                rv[k] -= ax;
            }
#pragma unroll
            for (int k = 0; k < 10; ++k) hr[k] = pw[TWP + k];
#pragma unroll
            for (int k = 0; k < 8; ++k) {
                float ax = ar3 * hr[k];
                ax = fmaf(ar4, hr[k + 1], ax);
                ax = fmaf(ar5, hr[k + 2], ax);
                rv[k] -= ax;
            }
#pragma unroll
            for (int k = 0; k < 10; ++k) hr[k] = pw[2 * TWP + k];
#pragma unroll
            for (int k = 0; k < 8; ++k) {
                float ax = ar6 * hr[k];
                ax = fmaf(ar7, hr[k + 1], ax);
                ax = fmaf(ar8, hr[k + 2], ax);
                float r = rv[k] - ax;
                rr = fmaf(r, r, rr);
            }
        }
        // block reduction (8 waves) -> one atomicAdd pair; LAST block finalizes
#pragma unroll
        for (int off = 32; off > 0; off >>= 1) {
            rr += __shfl_down(rr, off, 64);
            f2 += __shfl_down(f2, off, 64);
        }
        if ((t & 63) == 0) { sxraw[t >> 6] = rr; sxraw[8 + (t >> 6)] = f2; }
        __syncthreads();
        if (t == 0) {
            float sr = 0.f, sf = 0.f;
#pragma unroll
            for (int wv = 0; wv < 8; ++wv) { sr += sxraw[wv]; sf += sxraw[8 + wv]; }
            atomicAdd(&accp[0], sr);
            atomicAdd(&accp[1], sf);
            __threadfence();
            unsigned int done = atomicAdd((unsigned int*)accp + 2, 1u);
            if (done == (NN / OT) * (NN / OT) * BB - 1) {
                __threadfence();
                float rrt = atomicAdd(&accp[0], 0.f);
                float fft = atomicAdd(&accp[1], 0.f);
                outp[0] = sqrtf(rrt / fft);
            }
        }
    }
}

// ---------------------------------------------------------------------------
extern "C" void kernel_launch(void* const* d_in, const int* in_sizes, int n_in,
                              void* d_out, int out_size, void* d_ws, size_t ws_size,
                              hipStream_t stream) {
    const float* f  = (const float*)d_in[0];
    const float* kA = (const float*)d_in[1];
    float*       u  = (float*)d_in[2];   // scratch (fully overwritten by cycle 2)
    const float* W1 = (const float*)d_in[3];
    const float* b1 = (const float*)d_in[4];
    const float* W2 = (const float*)d_in[5];
    const float* b2 = (const float*)d_in[6];
    float* out = (float*)d_out;

    char* ws = (char*)d_ws;
    float* acc = (float*)ws;                                     // 12 B
    float* xB  = (float*)(ws + 256);                             // 16 MiB
    float* lfa = (float*)(ws + 256 + (size_t)BB * NN * NN * 4);  // 16 MiB

    lfa_kernel<<<dim3(1, NN / 2, BB), 256, 0, stream>>>(kA, lfa);

    dim3 jblk(32, 16);
    dim3 jgrd(NN / OT, NN / OT, BB);

    fused_cycle<true,  false><<<jgrd, jblk, 0, stream>>>(u, xB, f, kA, lfa, W1, b1, W2, b2, acc, out);
    fused_cycle<false, false><<<jgrd, jblk, 0, stream>>>(xB, u, f, kA, lfa, W1, b1, W2, b2, acc, out);
    fused_cycle<false, true ><<<jgrd, jblk, 0, stream>>>(u, xB, f, kA, lfa, W1, b1, W2, b2, acc, out);
}

// Round 10
// 352.068 us; speedup vs baseline: 1.0869x; 1.0869x over previous
//
#include <hip/hip_runtime.h>
#include <math.h>

#define BB 16
#define NN 512
#define HID 32

// Halos: vertical 12 (= contamination radius 10 sweeps + 1 ring + 1 A(H),
// margin 0), horizontal 16 (fixed by the 32-lane x 3-col geometry).
#define HALO_V 12
#define HALO_H 16
#define TWV 88       // tile rows  (64 + 2*12)
#define TWH 96       // tile cols  (64 + 2*16)
#define TWP 97       // LDS pitch: 97 % 32 == 1 -> conflict-free Phase D
#define OT 64
#define NR 11        // rows per thread (88 / 8)

// fast tanh-approx GELU: gelu(v) = v / (1 + exp2(K1*v + K2*v^3))
#define GELU_K1 (-2.302208201f)
#define GELU_K2 (-0.102944244f)

// LFA angle step 2*pi/513: rotation recurrence cos/sin
#define CDR 0.99992499f
#define SDR 0.012247618f
// 1/513 (angles in revolutions for v_sin_f32/v_cos_f32: D = sin(S0*2pi))
#define REVS 0.0019493177f

// ---------------------------------------------------------------------------
// LFA map (R10-proven + HW sin/cos, ~5 us). MEASURED (rounds 2 & 3): folding
// this into fused_cycle in ANY form tips it over the VGPR cliff. FROZEN.
// ---------------------------------------------------------------------------
__global__ __launch_bounds__(256) void lfa_kernel(const float* __restrict__ kernelA,
                                                  float* __restrict__ lfa) {
    const int t = threadIdx.x;
    const int strip = t & 127;           // 128 strips of 4 cols
    const int i = blockIdx.y * 2 + (t >> 7);
    const int b = blockIdx.z;
    const int j0 = strip * 4;
    const float* a = kernelA + b * 9;
    float a0 = a[0], a1 = a[1], a2 = a[2], a3 = a[3], a4 = a[4];
    float a5 = a[5], a6 = a[6], a7 = a[7], a8 = a[8];
    const float A35 = a3 + a5, A17 = a1 + a7, A08 = a0 + a8, A26 = a2 + a6;
    const float B53 = a5 - a3, B71 = a7 - a1, B80 = a8 - a0, B26 = a2 - a6;
    const float tau = 0.5f / a4;

    float r1 = (float)(j0 - NN / 2) * REVS;   // revolutions, |r| < 0.5
    float r2 = (float)(i - NN / 2) * REVS;
    float s1 = __builtin_amdgcn_sinf(r1);
    float c1 = __builtin_amdgcn_cosf(r1);
    float s2 = __builtin_amdgcn_sinf(r2);
    float c2 = __builtin_amdgcn_cosf(r2);

    float out[4];
#pragma unroll
    for (int k = 0; k < 4; ++k) {
        float cc = c1 * c2, ss = s1 * s2, sc = s1 * c2, cs = c1 * s2;
        float cpp = cc - ss, cpm = cc + ss, spp = sc + cs, spm = sc - cs;
        float re = fmaf(A35, c1, a4); re = fmaf(A17, c2, re);
        re = fmaf(A08, cpp, re);      re = fmaf(A26, cpm, re);
        float im = B53 * s1;          im = fmaf(B71, s2, im);
        im = fmaf(B80, spp, im);      im = fmaf(B26, spm, im);
        float zre = fmaf(-tau, re, 1.0f);
        float zim = tau * im;
        float m2 = fmaf(zre, zre, zim * zim);
        out[k] = m2 * m2 * sqrtf(m2);   // |z|^5
        float tt = s1 * SDR;
        float ns = fmaf(s1, CDR, c1 * SDR);
        c1 = fmaf(c1, CDR, -tt);
        s1 = ns;
    }
    float4 ov = {out[0], out[1], out[2], out[3]};
    *(float4*)(lfa + (size_t)b * NN * NN + (size_t)i * NN + j0) = ov;
}

// ---------------------------------------------------------------------------
// One full cycle. ROUND 10 = round-5 PROVEN skeleton (256 thr, 2 barriers
// per sweep, LDS border publish, 128-VGPR regime) with the VERTICAL HALO
// shrunk 16 -> 12 (tile 96 -> 88 rows, 11 rows/thread, -8.3% sweep work).
// Correctness: frozen tile row 0 corrupts rows 0..9 after 10 sweeps; row 10
// stays exact; RES ring row 11 reads rows 10..12 -> bit-exact, margin 0.
// Ledger: R8 (1-barrier+shuffles) 366 us = neutral; R9 (512thr occupancy)
// 382 us = negative; barriers/shuffles/occupancy are NOT the levers.
// DO NOT use multi-arg __launch_bounds__ (R1: 64-VGPR bucket + spills).
// DO NOT inline LFA (R2/R3: VGPR cliff). NEVER compress the 9-tap fma
// chains (R6/R7: dropped tap, absmax 3.9e-2).
// FIRST: x0 = 0, sweep 0 collapses to cur = mask*(tau*f); tile fill skipped;
//        zeroes the accumulator/counter slots (replaces hipMemsetAsync).
// RES:   cycle-3 variant (rounds 2/4/5/8 verified). No x store. r_final =
//        r_pre - A(H) via H-ring exchange through the LDS tile. Block-reduces
//        sum(r^2), sum(f^2); LAST block (device counter) computes the final
//        norm -> no finalize dispatch.
// ---------------------------------------------------------------------------
template <bool FIRST, bool RES>
__global__ __launch_bounds__(256) void fused_cycle(
        const float* __restrict__ xin, float* __restrict__ xout,
        const float* __restrict__ f, const float* __restrict__ kernelA,
        const float* __restrict__ lfa,
        const float* __restrict__ W1, const float* __restrict__ b1,
        const float* __restrict__ W2, const float* __restrict__ b2,
        float* __restrict__ accp, float* __restrict__ outp) {
    __shared__ float sxraw[90 * TWP + 2];   // rows -1..88, 34.9 KB
    float* sx = sxraw + TWP + 1;   // logical origin (0,0); row r col c -> sx[r*TWP+c]
    const int tx = threadIdx.x;   // 0..31
    const int ty = threadIdx.y;   // 0..7
    const int t  = ty * 32 + tx;
    const int b  = blockIdx.z;
    const int gy0 = blockIdx.y * OT;
    const int gx0 = blockIdx.x * OT;
    const int goi = gy0 - HALO_V;
    const int goj = gx0 - HALO_H;
    const float* fg = f + (size_t)b * NN * NN;
    const float* ag = kernelA + b * 9;   // uniform -> s_load
    const float ar0 = ag[0], ar1 = ag[1], ar2 = ag[2], ar3 = ag[3], ar4 = ag[4];
    const float ar5 = ag[5], ar6 = ag[6], ar7 = ag[7], ar8 = ag[8];
    const float tau = 0.5f / ar4;
    const float s0 = tau * ar0, q1 = tau * ar1, q2 = tau * ar2, q3 = tau * ar3;
    const float q4 = tau * ar4, q5 = tau * ar5, q6 = tau * ar6, q7 = tau * ar7;
    const float q8 = tau * ar8;

    if (FIRST) {
        if (t == 0 && (blockIdx.x | blockIdx.y | blockIdx.z) == 0) {
            accp[0] = 0.f;
            accp[1] = 0.f;
            ((unsigned int*)accp)[2] = 0u;
        }
    }

    // ---- zero the guard ring: row -1 (98), col -1 of rows 0..87 (== col 96
    // of rows -1..86), row 88 (98; includes col 96 of row 87)
    if (t < 98) sxraw[t] = 0.f;                 // row -1, cols -1..96
    if (t < 88) sxraw[97 + 97 * t] = 0.f;       // col -1 of row t
    if (t < 98) sxraw[89 * 97 + t] = 0.f;       // row 88, cols -1..96

    // ---- Phase A: tile -> LDS (88x96 interior), float4 strips ----
    if (!FIRST) {
        const float* xg = xin + (size_t)b * NN * NN;
#pragma unroll
        for (int k = 0; k < 9; ++k) {
            int idx = t + k * 256;           // 2112 strips (88 rows x 24)
            if (idx < 2112) {
                int row = idx / 24;
                int c4  = (idx - row * 24) * 4;
                int gi = goi + row, gj = goj + c4;
                float4 v = {0.f, 0.f, 0.f, 0.f};
                if ((unsigned)gi < NN && (unsigned)gj < NN)
                    v = *(const float4*)(xg + (size_t)gi * NN + gj);
                float* d = sx + row * TWP + c4;
                d[0] = v.x; d[1] = v.y; d[2] = v.z; d[3] = v.w;
            }
        }
    }

    const int R0 = ty * NR, C0 = tx * 3;
    const float* pb  = sx + (R0 - 1) * TWP + (C0 - 1);
    float*       pwv = sx + R0 * TWP + C0;

    float vR[NR], vC[3];
#pragma unroll
    for (int r = 0; r < NR; ++r) {
        int R = R0 + r, gi = goi + R;
        vR[r] = (R >= 1 && R < TWV - 1 && gi >= 0 && gi < NN) ? 1.f : 0.f;
    }
#pragma unroll
    for (int c = 0; c < 3; ++c) {
        int C = C0 + c, gj = goj + C;
        vC[c] = (C >= 1 && C < TWH - 1 && gj >= 0 && gj < NN) ? 1.f : 0.f;
    }

    float frt[NR][3];
#pragma unroll
    for (int r = 0; r < NR; ++r) {
        int gi = goi + R0 + r;
#pragma unroll
        for (int c = 0; c < 3; ++c) {
            int gj = goj + C0 + c;
            frt[r][c] = (gi >= 0 && gi < NN && gj >= 0 && gj < NN)
                            ? tau * fg[gi * NN + gj] : 0.f;
        }
    }

    __syncthreads();   // tile + guards visible

    // ---- Phase B: own cells -> registers ----
    float cur[NR][3];
    if (FIRST) {
        // collapsed sweep 0: x1 = mask * (tau*f); publish borders
#pragma unroll
        for (int r = 0; r < NR; ++r)
#pragma unroll
            for (int c = 0; c < 3; ++c)
                cur[r][c] = (vR[r] * vC[c]) * frt[r][c];
        pwv[0] = cur[0][0]; pwv[1] = cur[0][1]; pwv[2] = cur[0][2];
        pwv[10 * TWP] = cur[10][0]; pwv[10 * TWP + 1] = cur[10][1];
        pwv[10 * TWP + 2] = cur[10][2];
#pragma unroll
        for (int r = 1; r < 10; ++r) {
            pwv[r * TWP] = cur[r][0];
            pwv[r * TWP + 2] = cur[r][2];
        }
        __syncthreads();   // sweep-0 borders visible
    } else {
#pragma unroll
        for (int r = 0; r < NR; ++r) {
            cur[r][0] = pwv[r * TWP];
            cur[r][1] = pwv[r * TWP + 1];
            cur[r][2] = pwv[r * TWP + 2];
        }
    }

    // ---- Phase C: sweeps (FIRST starts at s=1: sweep 0 was collapsed) ----
    for (int s = FIRST ? 1 : 0; s < 10; ++s) {
        // halo reads, all immediate offsets off pb
        float top0 = pb[0], top1 = pb[1], top2 = pb[2], top3 = pb[3], top4 = pb[4];
        float bot0 = pb[12 * TWP],     bot1 = pb[12 * TWP + 1],
              bot2 = pb[12 * TWP + 2], bot3 = pb[12 * TWP + 3],
              bot4 = pb[12 * TWP + 4];
        float pm0 = top1, pm1v = top2, pm2 = top3;
        float Lm1 = top0, Rm1 = top4;
        float Lc = pb[TWP], Rc = pb[TWP + 4];
#pragma unroll
        for (int r = 0; r < NR; ++r) {
            float n0, n1, n2, Lp, Rp;
            if (r < NR - 1) {
                n0 = cur[r + 1][0]; n1 = cur[r + 1][1]; n2 = cur[r + 1][2];
                Lp = pb[(r + 2) * TWP];
                Rp = pb[(r + 2) * TWP + 4];
            } else {
                n0 = bot1; n1 = bot2; n2 = bot3; Lp = bot0; Rp = bot4;
            }
            float o0 = cur[r][0], o1 = cur[r][1], o2 = cur[r][2];
            // c = 0  (canonical 9-tap)
            {
                float ax = s0 * Lm1;
                ax = fmaf(q1, pm0, ax); ax = fmaf(q2, pm1v, ax);
                ax = fmaf(q3, Lc, ax);  ax = fmaf(q4, o0, ax);
                ax = fmaf(q5, o1, ax);  ax = fmaf(q6, Lp, ax);
                ax = fmaf(q7, n0, ax);  ax = fmaf(q8, n1, ax);
                cur[r][0] = fmaf(vR[r] * vC[0], frt[r][0] - ax, o0);
            }
            // c = 1
            {
                float ax = s0 * pm0;
                ax = fmaf(q1, pm1v, ax); ax = fmaf(q2, pm2, ax);
                ax = fmaf(q3, o0, ax);   ax = fmaf(q4, o1, ax);
                ax = fmaf(q5, o2, ax);   ax = fmaf(q6, n0, ax);
                ax = fmaf(q7, n1, ax);   ax = fmaf(q8, n2, ax);
                cur[r][1] = fmaf(vR[r] * vC[1], frt[r][1] - ax, o1);
            }
            // c = 2
            {
                float ax = s0 * pm1v;
                ax = fmaf(q1, pm2, ax); ax = fmaf(q2, Rm1, ax);
                ax = fmaf(q3, o1, ax);  ax = fmaf(q4, o2, ax);
                ax = fmaf(q5, Rc, ax);  ax = fmaf(q6, n1, ax);
                ax = fmaf(q7, n2, ax);  ax = fmaf(q8, Rp, ax);
                cur[r][2] = fmaf(vR[r] * vC[2], frt[r][2] - ax, o2);
            }
            pm0 = o0; pm1v = o1; pm2 = o2;
            Lm1 = Lc; Rm1 = Rc; Lc = Lp; Rc = Rp;
        }
        __syncthreads();   // all halo reads done
        if (s < 9) {
            // publish border cells (24): rows 0/10 full, rows 1..9 cols 0/2
            pwv[0] = cur[0][0]; pwv[1] = cur[0][1]; pwv[2] = cur[0][2];
            pwv[10 * TWP] = cur[10][0]; pwv[10 * TWP + 1] = cur[10][1];
            pwv[10 * TWP + 2] = cur[10][2];
#pragma unroll
            for (int r = 1; r < 10; ++r) {
                pwv[r * TWP] = cur[r][0];
                pwv[r * TWP + 2] = cur[r][2];
            }
        } else {
            // final sweep: publish ALL cells for the correction phase
#pragma unroll
            for (int r = 0; r < NR; ++r) {
                pwv[r * TWP] = cur[r][0];
                pwv[r * TWP + 1] = cur[r][1];
                pwv[r * TWP + 2] = cur[r][2];
            }
        }
        __syncthreads();   // writes visible
    }

    // ---- Phase D: remapped correction, exactly 1x MLP work ----
    // thread t -> output row orow = t/4 (0..63), column segment oseg = t%4
    const int orow = t >> 2;
    const int oseg = t & 3;
    const int Rl = HALO_V + orow;          // 12..75
    const int Cl0 = HALO_H + oseg * 16;    // 16,32,48,64
    const float* pw = sx + (Rl - 1) * TWP + (Cl0 - 1);
    const int gi = gy0 + orow;
    const int gjb = gx0 + oseg * 16;
    const float b2v = b2[0];

    if (!RES) {
        float w0[18], w1[18], w2[18];
#pragma unroll
        for (int k = 0; k < 18; ++k) {
            w0[k] = pw[k];
            w1[k] = pw[TWP + k];
            w2[k] = pw[2 * TWP + k];
        }
        const float4* f4 = (const float4*)(fg + (size_t)gi * NN + gjb);
        const float4* l4 = (const float4*)(lfa + (size_t)b * NN * NN + (size_t)gi * NN + gjb);
        float fv[16], lv[16];
#pragma unroll
        for (int q = 0; q < 4; ++q) {
            float4 fq = f4[q], lq = l4[q];
            fv[q * 4] = fq.x; fv[q * 4 + 1] = fq.y; fv[q * 4 + 2] = fq.z; fv[q * 4 + 3] = fq.w;
            lv[q * 4] = lq.x; lv[q * 4 + 1] = lq.y; lv[q * 4 + 2] = lq.z; lv[q * 4 + 3] = lq.w;
        }
        float rv[16];
#pragma unroll
        for (int k = 0; k < 16; ++k) {
            float ax = ar0 * w0[k];
            ax = fmaf(ar1, w0[k + 1], ax); ax = fmaf(ar2, w0[k + 2], ax);
            ax = fmaf(ar3, w1[k], ax);     ax = fmaf(ar4, w1[k + 1], ax);
            ax = fmaf(ar5, w1[k + 2], ax); ax = fmaf(ar6, w2[k], ax);
            ax = fmaf(ar7, w2[k + 1], ax); ax = fmaf(ar8, w2[k + 2], ax);
            rv[k] = fv[k] - ax;
        }
        float acc[16];
#pragma unroll
        for (int k = 0; k < 16; ++k) acc[k] = 0.f;
        for (int hh = 0; hh < HID; ++hh) {
            float w1a = W1[2 * hh], w1b = W1[2 * hh + 1], bb = b1[hh], wo = W2[hh];
#pragma unroll
            for (int k = 0; k < 16; ++k) {
                float v = fmaf(w1a, lv[k], fmaf(w1b, rv[k], bb));
                float m = v * fmaf(GELU_K2, v * v, GELU_K1);
                float e2 = __builtin_amdgcn_exp2f(m);
                float g = v * __builtin_amdgcn_rcpf(1.0f + e2);
                acc[k] = fmaf(wo, g, acc[k]);
            }
        }
        float4* xo4 = (float4*)(xout + (size_t)b * NN * NN + (size_t)gi * NN + gjb);
#pragma unroll
        for (int q = 0; q < 4; ++q) {
            float4 ov;
            ov.x = w1[q * 4 + 1] + acc[q * 4] + b2v;
            ov.y = w1[q * 4 + 2] + acc[q * 4 + 1] + b2v;
            ov.z = w1[q * 4 + 3] + acc[q * 4 + 2] + b2v;
            ov.w = w1[q * 4 + 4] + acc[q * 4 + 3] + b2v;
            xo4[q] = ov;
        }
    } else {
        // register-light residual path (rounds 2/4/5 verified)
        float rv[16];
        {
            float w[18];
#pragma unroll
            for (int k = 0; k < 18; ++k) w[k] = pw[k];
#pragma unroll
            for (int k = 0; k < 16; ++k) {
                float ax = ar0 * w[k];
                ax = fmaf(ar1, w[k + 1], ax);
                rv[k] = fmaf(ar2, w[k + 2], ax);
            }
#pragma unroll
            for (int k = 0; k < 18; ++k) w[k] = pw[TWP + k];
#pragma unroll
            for (int k = 0; k < 16; ++k) {
                float ax = fmaf(ar3, w[k], rv[k]);
                ax = fmaf(ar4, w[k + 1], ax);
                rv[k] = fmaf(ar5, w[k + 2], ax);
            }
#pragma unroll
            for (int k = 0; k < 18; ++k) w[k] = pw[2 * TWP + k];
#pragma unroll
            for (int k = 0; k < 16; ++k) {
                float ax = fmaf(ar6, w[k], rv[k]);
                ax = fmaf(ar7, w[k + 1], ax);
                rv[k] = fmaf(ar8, w[k + 2], ax);
            }
        }
        float f2 = 0.f;
        {
            const float4* f4 = (const float4*)(fg + (size_t)gi * NN + gjb);
#pragma unroll
            for (int q = 0; q < 4; ++q) {
                float4 fq = f4[q];
                rv[q * 4]     = fq.x - rv[q * 4];
                rv[q * 4 + 1] = fq.y - rv[q * 4 + 1];
                rv[q * 4 + 2] = fq.z - rv[q * 4 + 2];
                rv[q * 4 + 3] = fq.w - rv[q * 4 + 3];
                f2 = fmaf(fq.x, fq.x, f2);
                f2 = fmaf(fq.y, fq.y, f2);
                f2 = fmaf(fq.z, fq.z, f2);
                f2 = fmaf(fq.w, fq.w, f2);
            }
        }

        // ---- ring-cell H: the 66x66 frame around the 64x64 output region.
        // Ring rows 11/76, cols 15/80 (HALO_V=12, HALO_H=16). Ring values
        // need w rows 10..77 / cols 14..81: exact (contamination stops at
        // rows 9/78, cols 13/82). 260 cells: t takes one, t<4 take two.
        float Hr0 = 0.f, Hr1 = 0.f;
        int hoff0 = 0, hoff1 = 0;
        auto ringH = [&](int rc, float& Hv, int& hoff) {
            int R, C;
            if (rc < 66)       { R = 11; C = 15 + rc; }
            else if (rc < 132) { R = 76; C = rc - 51; }
            else if (rc < 196) { R = rc - 120; C = 15; }
            else               { R = rc - 184; C = 80; }
            hoff = R * TWP + C;
            int rgi = goi + R, rgj = goj + C;
            Hv = 0.f;
            if (rgi >= 0 && rgi < NN && rgj >= 0 && rgj < NN) {
                const float* pr = sx + (R - 1) * TWP + (C - 1);
                float u0 = pr[0], u1 = pr[1], u2 = pr[2];
                float m0 = pr[TWP], m1 = pr[TWP + 1], m2 = pr[TWP + 2];
                float d0 = pr[2 * TWP], d1 = pr[2 * TWP + 1], d2 = pr[2 * TWP + 2];
                float ax = ar0 * u0;
                ax = fmaf(ar1, u1, ax); ax = fmaf(ar2, u2, ax);
                ax = fmaf(ar3, m0, ax); ax = fmaf(ar4, m1, ax);
                ax = fmaf(ar5, m2, ax); ax = fmaf(ar6, d0, ax);
                ax = fmaf(ar7, d1, ax); ax = fmaf(ar8, d2, ax);
                float rp = fg[(size_t)rgi * NN + rgj] - ax;
                float lf = lfa[(size_t)b * NN * NN + (size_t)rgi * NN + rgj];
                float av = 0.f;
                for (int hh = 0; hh < HID; ++hh) {
                    float w1a = W1[2 * hh], w1b = W1[2 * hh + 1], bbv = b1[hh], wo = W2[hh];
                    float v = fmaf(w1a, lf, fmaf(w1b, rp, bbv));
                    float m = v * fmaf(GELU_K2, v * v, GELU_K1);
                    float e2 = __builtin_amdgcn_exp2f(m);
                    float gg = v * __builtin_amdgcn_rcpf(1.0f + e2);
                    av = fmaf(wo, gg, av);
                }
                Hv = av + b2v;
            }
        };
        ringH(t, Hr0, hoff0);
        if (t < 4) ringH(t + 256, Hr1, hoff1);

        // ---- own-cell MLP: lv loaded just-in-time ----
        float acc[16];
#pragma unroll
        for (int k = 0; k < 16; ++k) acc[k] = 0.f;
        {
            float lv[16];
            const float4* l4 = (const float4*)(lfa + (size_t)b * NN * NN + (size_t)gi * NN + gjb);
#pragma unroll
            for (int q = 0; q < 4; ++q) {
                float4 lq = l4[q];
                lv[q * 4] = lq.x; lv[q * 4 + 1] = lq.y;
                lv[q * 4 + 2] = lq.z; lv[q * 4 + 3] = lq.w;
            }
            for (int hh = 0; hh < HID; ++hh) {
                float w1a = W1[2 * hh], w1b = W1[2 * hh + 1], bb = b1[hh], wo = W2[hh];
#pragma unroll
                for (int k = 0; k < 16; ++k) {
                    float v = fmaf(w1a, lv[k], fmaf(w1b, rv[k], bb));
                    float m = v * fmaf(GELU_K2, v * v, GELU_K1);
                    float e2 = __builtin_amdgcn_exp2f(m);
                    float g = v * __builtin_amdgcn_rcpf(1.0f + e2);
                    acc[k] = fmaf(wo, g, acc[k]);
                }
            }
        }

        __syncthreads();   // all LDS w-reads (own + ring) complete
        // publish H on rows 11..76 x cols 15..80 in place over the sweep tile
        float* ph = sx + Rl * TWP + Cl0;
#pragma unroll
        for (int k = 0; k < 16; ++k) ph[k] = acc[k] + b2v;
        sx[hoff0] = Hr0;
        if (t < 4) sx[hoff1] = Hr1;
        __syncthreads();   // H tile visible

        // r_final = r_pre - A(H), row-by-row
        float rr = 0.f;
        {
            float hr[18];
#pragma unroll
            for (int k = 0; k < 18; ++k) hr[k] = pw[k];
#pragma unroll
            for (int k = 0; k < 16; ++k) {
                float ax = ar0 * hr[k];
                ax = fmaf(ar1, hr[k + 1], ax);
                ax = fmaf(ar2, hr[k + 2], ax);
                rv[k] -= ax;
            }
#pragma unroll
            for (int k = 0; k < 18; ++k) hr[k] = pw[TWP + k];
#pragma unroll
            for (int k = 0; k < 16; ++k) {
                float ax = ar3 * hr[k];
                ax = fmaf(ar4, hr[k + 1], ax);
                ax = fmaf(ar5, hr[k + 2], ax);
                rv[k] -= ax;
            }
#pragma unroll
            for (int k = 0; k < 18; ++k) hr[k] = pw[2 * TWP + k];
#pragma unroll
            for (int k = 0; k < 16; ++k) {
                float ax = ar6 * hr[k];
                ax = fmaf(ar7, hr[k + 1], ax);
                ax = fmaf(ar8, hr[k + 2], ax);
                float r = rv[k] - ax;
                rr = fmaf(r, r, rr);
            }
        }
        // block reduction -> one atomicAdd pair; LAST block finalizes
#pragma unroll
        for (int off = 32; off > 0; off >>= 1) {
            rr += __shfl_down(rr, off, 64);
            f2 += __shfl_down(f2, off, 64);
        }
        if ((t & 63) == 0) { sxraw[t >> 6] = rr; sxraw[4 + (t >> 6)] = f2; }
        __syncthreads();
        if (t == 0) {
            atomicAdd(&accp[0], sxraw[0] + sxraw[1] + sxraw[2] + sxraw[3]);
            atomicAdd(&accp[1], sxraw[4] + sxraw[5] + sxraw[6] + sxraw[7]);
            __threadfence();
            unsigned int done = atomicAdd((unsigned int*)accp + 2, 1u);
            if (done == (NN / OT) * (NN / OT) * BB - 1) {
                __threadfence();
                float rrt = atomicAdd(&accp[0], 0.f);
                float fft = atomicAdd(&accp[1], 0.f);
                outp[0] = sqrtf(rrt / fft);
            }
        }
    }
}

// ---------------------------------------------------------------------------
extern "C" void kernel_launch(void* const* d_in, const int* in_sizes, int n_in,
                              void* d_out, int out_size, void* d_ws, size_t ws_size,
                              hipStream_t stream) {
    const float* f  = (const float*)d_in[0];
    const float* kA = (const float*)d_in[1];
    float*       u  = (float*)d_in[2];   // scratch (fully overwritten by cycle 2)
    const float* W1 = (const float*)d_in[3];
    const float* b1 = (const float*)d_in[4];
    const float* W2 = (const float*)d_in[5];
    const float* b2 = (const float*)d_in[6];
    float* out = (float*)d_out;

    char* ws = (char*)d_ws;
    float* acc = (float*)ws;                                     // 12 B
    float* xB  = (float*)(ws + 256);                             // 16 MiB
    float* lfa = (float*)(ws + 256 + (size_t)BB * NN * NN * 4);  // 16 MiB

    lfa_kernel<<<dim3(1, NN / 2, BB), 256, 0, stream>>>(kA, lfa);

    dim3 jblk(32, 8);
    dim3 jgrd(NN / OT, NN / OT, BB);

    fused_cycle<true,  false><<<jgrd, jblk, 0, stream>>>(u, xB, f, kA, lfa, W1, b1, W2, b2, acc, out);
    fused_cycle<false, false><<<jgrd, jblk, 0, stream>>>(xB, u, f, kA, lfa, W1, b1, W2, b2, acc, out);
    fused_cycle<false, true ><<<jgrd, jblk, 0, stream>>>(u, xB, f, kA, lfa, W1, b1, W2, b2, acc, out);
}